// Round 1
// baseline (1199.669 us; speedup 1.0000x reference)
//
#include <hip/hip_runtime.h>

#define CIN 256
#define COUT 256
#define HH 32
#define WW 32
#define LL 4
#define NN 64   // B*L

// ---------------- Kernel 1: spatial mean pool ----------------
// pooled[n*CIN + ci] = mean over 32x32 of x[n][ci]
__global__ __launch_bounds__(256) void pool_kernel(const float* __restrict__ x,
                                                   float* __restrict__ pooled) {
    int blk = blockIdx.x;                    // n*CIN + ci
    const float* src = x + (size_t)blk * (HH * WW);
    int tid = threadIdx.x;
    float4 v = ((const float4*)src)[tid];    // 256 threads * 4 = 1024
    float s = v.x + v.y + v.z + v.w;
    #pragma unroll
    for (int off = 32; off > 0; off >>= 1) s += __shfl_down(s, off, 64);
    __shared__ float ws[4];
    if ((tid & 63) == 0) ws[tid >> 6] = s;
    __syncthreads();
    if (tid == 0) {
        pooled[blk] = (ws[0] + ws[1] + ws[2] + ws[3]) * (1.0f / (HH * WW));
    }
}

// ---------------- Kernel 2: temporal calib + gate ----------------
// scale[n*CIN + co] = calib + 1 ; gmul[n] = gate + 1
__global__ __launch_bounds__(256) void calib_kernel(const float* __restrict__ pooled,
                                                    const float* __restrict__ tconv_w,
                                                    const float* __restrict__ tconv_b,
                                                    const float* __restrict__ fc_w,
                                                    const float* __restrict__ fc_b,
                                                    float* __restrict__ scale,
                                                    float* __restrict__ gmul) {
    int n = blockIdx.x;          // b*L + t
    int b = n / LL, t = n % LL;
    int i0 = max(t - 2, 0), i1 = max(t - 1, 0), i2 = t;
    __shared__ float p[3][CIN];
    int tid = threadIdx.x;       // 256 = CIN
    p[0][tid] = pooled[(b * LL + i0) * CIN + tid];
    p[1][tid] = pooled[(b * LL + i1) * CIN + tid];
    p[2][tid] = pooled[(b * LL + i2) * CIN + tid];
    __syncthreads();
    // calib for tconv output channel co = tid
    float acc = 0.f;
    for (int ci = 0; ci < CIN; ci++) {
        const float* w = tconv_w + ((size_t)tid * CIN + ci) * 3;
        acc += p[0][ci] * w[0] + p[1][ci] * w[1] + p[2][ci] * w[2];
    }
    scale[n * CIN + tid] = acc + tconv_b[tid] + 1.0f;
    // gate (single output channel): each thread contributes its ci = tid
    const float* fw = fc_w + tid * 3;
    float g = p[0][tid] * fw[0] + p[1][tid] * fw[1] + p[2][tid] * fw[2];
    #pragma unroll
    for (int off = 32; off > 0; off >>= 1) g += __shfl_down(g, off, 64);
    __shared__ float gw[4];
    if ((tid & 63) == 0) gw[tid >> 6] = g;
    __syncthreads();
    if (tid == 0) gmul[n] = gw[0] + gw[1] + gw[2] + gw[3] + fc_b[0] + 1.0f;
}

// ---------------- Kernel 3: direct conv2d, input pre-scaled at stage ----------------
// Block: one (n, co-group of 64, row-group of 4). 256 threads:
//   c = tid&31 (output col), sub = tid>>5 (0..7): co = co_base + sub*8 + j
// acc[8][4] per thread = 8 co x 4 rows x 1 col.
__global__ __launch_bounds__(256) void conv_kernel(const float* __restrict__ x,
                                                   const float* __restrict__ weight,
                                                   const float* __restrict__ bias,
                                                   const float* __restrict__ scale,
                                                   const float* __restrict__ gmul,
                                                   float* __restrict__ out) {
    int blk = blockIdx.x;
    int n   = blk >> 5;           // 32 blocks per sample
    int cog = (blk >> 3) & 3;
    int rg  = blk & 7;
    int co_base  = cog * 64;
    int row_base = rg * 4;
    int tid = threadIdx.x;
    int c   = tid & 31;
    int sub = tid >> 5;

    __shared__ float xin[6][34];     // halo'd input tile for one ci
    __shared__ float wsh[9][65];     // [k][co] padded (conflict-free writes)

    float acc[8][4];
    #pragma unroll
    for (int j = 0; j < 8; j++)
        #pragma unroll
        for (int g = 0; g < 4; g++) acc[j][g] = 0.f;

    const float* xn = x + (size_t)n * CIN * HH * WW;

    for (int ci = 0; ci < CIN; ci++) {
        // ---- stage scaled input tile: rows row_base-1 .. row_base+4, cols -1..32
        if (tid < 204) {
            float s = scale[n * CIN + ci];
            int lr = tid / 34, lc = tid % 34;
            int gr = row_base - 1 + lr, gc = lc - 1;
            float v = 0.f;
            if (gr >= 0 && gr < HH && gc >= 0 && gc < WW)
                v = xn[(size_t)ci * (HH * WW) + gr * WW + gc] * s;
            xin[lr][lc] = v;
        }
        // ---- stage weights for this ci: 64 co x 9
        for (int idx = tid; idx < 576; idx += 256) {
            int co = idx / 9, k = idx % 9;
            wsh[k][co] = weight[(size_t)(co_base + co) * (CIN * 9) + ci * 9 + k];
        }
        __syncthreads();

        float xr[6][3];
        #pragma unroll
        for (int r = 0; r < 6; r++)
            #pragma unroll
            for (int kw = 0; kw < 3; kw++)
                xr[r][kw] = xin[r][c + kw];

        #pragma unroll
        for (int j = 0; j < 8; j++) {
            float wv[9];
            #pragma unroll
            for (int k = 0; k < 9; k++) wv[k] = wsh[k][sub * 8 + j];
            #pragma unroll
            for (int g = 0; g < 4; g++)
                #pragma unroll
                for (int kh = 0; kh < 3; kh++)
                    #pragma unroll
                    for (int kw = 0; kw < 3; kw++)
                        acc[j][g] += xr[g + kh][kw] * wv[kh * 3 + kw];
        }
        __syncthreads();
    }

    float gm = gmul[n];
    #pragma unroll
    for (int j = 0; j < 8; j++) {
        int co = co_base + sub * 8 + j;
        float fb = bias[co] * gm;
        #pragma unroll
        for (int g = 0; g < 4; g++) {
            out[(((size_t)n * COUT + co) * HH + (row_base + g)) * WW + c] = acc[j][g] + fb;
        }
    }
}

extern "C" void kernel_launch(void* const* d_in, const int* in_sizes, int n_in,
                              void* d_out, int out_size, void* d_ws, size_t ws_size,
                              hipStream_t stream) {
    const float* x       = (const float*)d_in[0];
    const float* weight  = (const float*)d_in[1];
    const float* bias    = (const float*)d_in[2];
    const float* tconv_w = (const float*)d_in[3];
    const float* tconv_b = (const float*)d_in[4];
    const float* fc_w    = (const float*)d_in[5];
    const float* fc_b    = (const float*)d_in[6];
    float* out = (float*)d_out;

    float* pooled = (float*)d_ws;                 // NN*CIN = 16384 floats
    float* scale  = pooled + NN * CIN;            // NN*CIN
    float* gmul   = scale + NN * CIN;             // NN

    pool_kernel<<<NN * CIN, 256, 0, stream>>>(x, pooled);
    calib_kernel<<<NN, 256, 0, stream>>>(pooled, tconv_w, tconv_b, fc_w, fc_b, scale, gmul);
    conv_kernel<<<NN * 32, 256, 0, stream>>>(x, weight, bias, scale, gmul, out);
}

// Round 2
// 148.689 us; speedup vs baseline: 8.0683x; 8.0683x over previous
//
#include <hip/hip_runtime.h>
#include <hip/hip_bf16.h>

#define CIN 256
#define COUT 256
#define HH 32
#define WW 32
#define LL 4
#define NN 64   // B*L

typedef unsigned short u16;
typedef __attribute__((ext_vector_type(8))) short short8;   // 8 bf16 (4 VGPRs)
typedef __attribute__((ext_vector_type(4))) float f32x4;

static __device__ __forceinline__ u16 f2bf(float f) {
    __hip_bfloat16 h = __float2bfloat16(f);
    return *reinterpret_cast<u16*>(&h);
}

// ---------------- Kernel 1: spatial mean pool ----------------
__global__ __launch_bounds__(256) void pool_kernel(const float* __restrict__ x,
                                                   float* __restrict__ pooled) {
    int blk = blockIdx.x;                    // n*CIN + ci
    const float* src = x + (size_t)blk * (HH * WW);
    int tid = threadIdx.x;
    float4 v = ((const float4*)src)[tid];
    float s = v.x + v.y + v.z + v.w;
    #pragma unroll
    for (int off = 32; off > 0; off >>= 1) s += __shfl_down(s, off, 64);
    __shared__ float ws[4];
    if ((tid & 63) == 0) ws[tid >> 6] = s;
    __syncthreads();
    if (tid == 0) pooled[blk] = (ws[0] + ws[1] + ws[2] + ws[3]) * (1.0f / (HH * WW));
}

// ---------------- Kernel 2: temporal calib + gate ----------------
__global__ __launch_bounds__(256) void calib_kernel(const float* __restrict__ pooled,
                                                    const float* __restrict__ tconv_w,
                                                    const float* __restrict__ tconv_b,
                                                    const float* __restrict__ fc_w,
                                                    const float* __restrict__ fc_b,
                                                    float* __restrict__ scale,
                                                    float* __restrict__ gmul) {
    int n = blockIdx.x;
    int b = n / LL, t = n % LL;
    int i0 = max(t - 2, 0), i1 = max(t - 1, 0), i2 = t;
    __shared__ float p[3][CIN];
    int tid = threadIdx.x;
    p[0][tid] = pooled[(b * LL + i0) * CIN + tid];
    p[1][tid] = pooled[(b * LL + i1) * CIN + tid];
    p[2][tid] = pooled[(b * LL + i2) * CIN + tid];
    __syncthreads();
    float acc = 0.f;
    for (int ci = 0; ci < CIN; ci++) {
        const float* w = tconv_w + ((size_t)tid * CIN + ci) * 3;
        acc += p[0][ci] * w[0] + p[1][ci] * w[1] + p[2][ci] * w[2];
    }
    scale[n * CIN + tid] = acc + tconv_b[tid] + 1.0f;
    const float* fw = fc_w + tid * 3;
    float g = p[0][tid] * fw[0] + p[1][tid] * fw[1] + p[2][tid] * fw[2];
    #pragma unroll
    for (int off = 32; off > 0; off >>= 1) g += __shfl_down(g, off, 64);
    __shared__ float gw[4];
    if ((tid & 63) == 0) gw[tid >> 6] = g;
    __syncthreads();
    if (tid == 0) gmul[n] = gw[0] + gw[1] + gw[2] + gw[3] + fc_b[0] + 1.0f;
}

// ---------------- Kernel 3a: xs_pad[n][34][34][ci] = bf16(x * scale), borders zeroed separately
__global__ __launch_bounds__(256) void xs_prep_kernel(const float* __restrict__ x,
                                                      const float* __restrict__ scale,
                                                      u16* __restrict__ xs) {
    int blk = blockIdx.x;            // n*32 + h
    int n = blk >> 5, h = blk & 31;
    __shared__ float tile[64][33];   // padded: conflict-free transpose
    int tid = threadIdx.x;
    for (int c0 = 0; c0 < CIN; c0 += 64) {
        #pragma unroll
        for (int r = 0; r < 8; r++) {
            int idx = r * 256 + tid;             // 2048 = 64ci x 32w
            int ci = idx >> 5, w = idx & 31;
            tile[ci][w] = x[(((size_t)n * CIN + c0 + ci) * HH + h) * WW + w];
        }
        __syncthreads();
        #pragma unroll
        for (int r = 0; r < 8; r++) {
            int idx = r * 256 + tid;
            int w = idx >> 6, cl = idx & 63;
            float v = tile[cl][w] * scale[n * CIN + c0 + cl];
            xs[(((size_t)n * 34 + h + 1) * 34 + (w + 1)) * CIN + c0 + cl] = f2bf(v);
        }
        __syncthreads();
    }
}

// ---------------- Kernel 3b: zero the pad border of xs
__global__ __launch_bounds__(256) void border_kernel(u16* __restrict__ xs) {
    int n = blockIdx.x;
    for (int idx = threadIdx.x; idx < 132 * 256; idx += 256) {
        int cell = idx >> 8, ci = idx & 255;
        int hp, wp;
        if (cell < 34)       { hp = 0;              wp = cell; }
        else if (cell < 68)  { hp = 33;             wp = cell - 34; }
        else if (cell < 100) { hp = cell - 68 + 1;  wp = 0; }
        else                 { hp = cell - 100 + 1; wp = 33; }
        xs[(((size_t)n * 34 + hp) * 34 + wp) * CIN + ci] = 0;
    }
}

// ---------------- Kernel 3c: wb[tap][co][ci] = bf16(weight[co][ci][tap])
__global__ __launch_bounds__(256) void wprep_kernel(const float* __restrict__ weight,
                                                    u16* __restrict__ wb) {
    int co = blockIdx.x;
    __shared__ u16 t[9][256];
    int ci = threadIdx.x;
    #pragma unroll
    for (int k = 0; k < 9; k++)
        t[k][ci] = f2bf(weight[((size_t)co * CIN + ci) * 9 + k]);
    __syncthreads();
    #pragma unroll
    for (int k = 0; k < 9; k++)
        wb[(size_t)k * COUT * CIN + (size_t)co * CIN + ci] = t[k][ci];
}

// ---------------- Kernel 4: MFMA implicit-GEMM conv ----------------
// Block: (n, cog of 64 co, pt of 8 output rows). 4 waves; wave = 64co x 64pos(2 rows).
// K loop: 8 chunks of 32 ci; per chunk 9 taps x 16 MFMA per wave against staged LDS.
__global__ __launch_bounds__(256, 2) void conv_mfma_kernel(
    const u16* __restrict__ xs, const u16* __restrict__ wb,
    const float* __restrict__ bias, const float* __restrict__ gmul,
    float* __restrict__ out) {
    int blk = blockIdx.x;
    int n = blk >> 4, cog = (blk >> 2) & 3, pt = blk & 3;
    int r0 = pt * 8;
    int tid = threadIdx.x;
    int lane = tid & 63, wave = tid >> 6;
    int l15 = lane & 15, l4 = lane >> 4;   // l4 = k-octet 0..3
    int wr = wave * 2;                      // wave's output-row offset within tile

    __shared__ u16 Alds[9 * 64 * 32];   // 36864 B, swizzled flat
    __shared__ u16 Blds[10 * 34 * 32];  // 21760 B, swizzled flat

    f32x4 acc[4][4];
    #pragma unroll
    for (int m = 0; m < 4; m++)
        #pragma unroll
        for (int nr = 0; nr < 4; nr++) acc[m][nr] = (f32x4){0.f, 0.f, 0.f, 0.f};

    const u16* xs_n = xs + (size_t)n * 34 * 34 * CIN;
    const u16* wb_c = wb + (size_t)cog * 64 * CIN;

    for (int kc = 0; kc < 8; kc++) {
        int ci0 = kc * 32;
        __syncthreads();
        // ---- stage A: [9 taps][64 co][32 ci] = 2304 x 16B units
        #pragma unroll
        for (int r = 0; r < 9; r++) {
            int u = r * 256 + tid;
            int t_ = u >> 8, co = (u >> 2) & 63, k8 = u & 3;
            short8 v = *(const short8*)(wb_c + (size_t)t_ * COUT * CIN + co * CIN + ci0 + k8 * 8);
            int row64 = t_ * 64 + co;
            int byt = (u * 16) ^ ((row64 & 3) << 4);
            *(short8*)((char*)Alds + byt) = v;
        }
        // ---- stage B: [10 rows][34 cols][32 ci] = 1360 x 16B units
        #pragma unroll
        for (int r = 0; r < 6; r++) {
            int u = r * 256 + tid;
            if (u < 1360) {
                int pos = u >> 2, k8 = u & 3;
                int lrow = pos / 34, lcol = pos - lrow * 34;
                short8 v = *(const short8*)(xs_n + ((size_t)(r0 + lrow) * 34 + lcol) * CIN + ci0 + k8 * 8);
                int byt = (u * 16) ^ ((pos & 3) << 4);
                *(short8*)((char*)Blds + byt) = v;
            }
        }
        __syncthreads();

        #pragma unroll
        for (int tp = 0; tp < 9; tp++) {
            const int dh = tp / 3, dw = tp % 3;
            short8 af[4], bf[4];
            #pragma unroll
            for (int m = 0; m < 4; m++) {
                int row64 = tp * 64 + m * 16 + l15;
                int byt = (row64 * 64 + l4 * 16) ^ ((row64 & 3) << 4);
                af[m] = *(const short8*)((const char*)Alds + byt);
            }
            #pragma unroll
            for (int nr = 0; nr < 4; nr++) {
                int rr = nr >> 1, ch = nr & 1;
                int pos = (wr + rr + dh) * 34 + ch * 16 + l15 + dw;
                int byt = (pos * 64 + l4 * 16) ^ ((pos & 3) << 4);
                bf[nr] = *(const short8*)((const char*)Blds + byt);
            }
            #pragma unroll
            for (int m = 0; m < 4; m++)
                #pragma unroll
                for (int nr = 0; nr < 4; nr++)
                    acc[m][nr] = __builtin_amdgcn_mfma_f32_16x16x32_bf16(af[m], bf[nr], acc[m][nr], 0, 0, 0);
        }
    }

    // ---- epilogue: D row=(l>>4)*4+j (co), col=l&15 (pos)  [guide-verified C/D layout]
    float gm = gmul[n];
    #pragma unroll
    for (int m = 0; m < 4; m++) {
        #pragma unroll
        for (int nr = 0; nr < 4; nr++) {
            int rr = nr >> 1, ch = nr & 1;
            int orow = r0 + wr + rr;
            #pragma unroll
            for (int j = 0; j < 4; j++) {
                int co = cog * 64 + m * 16 + l4 * 4 + j;
                out[(((size_t)n * COUT + co) * HH + orow) * WW + ch * 16 + l15] =
                    acc[m][nr][j] + bias[co] * gm;
            }
        }
    }
}

// ---------------- Fallback fp32 direct conv (if ws too small) ----------------
__global__ __launch_bounds__(256) void conv_kernel(const float* __restrict__ x,
                                                   const float* __restrict__ weight,
                                                   const float* __restrict__ bias,
                                                   const float* __restrict__ scale,
                                                   const float* __restrict__ gmul,
                                                   float* __restrict__ out) {
    int blk = blockIdx.x;
    int n   = blk >> 5;
    int cog = (blk >> 3) & 3;
    int rg  = blk & 7;
    int co_base  = cog * 64;
    int row_base = rg * 4;
    int tid = threadIdx.x;
    int c   = tid & 31;
    int sub = tid >> 5;

    __shared__ float xin[6][34];
    __shared__ float wsh[9][65];

    float acc[8][4];
    #pragma unroll
    for (int j = 0; j < 8; j++)
        #pragma unroll
        for (int g = 0; g < 4; g++) acc[j][g] = 0.f;

    const float* xn = x + (size_t)n * CIN * HH * WW;

    for (int ci = 0; ci < CIN; ci++) {
        if (tid < 204) {
            float s = scale[n * CIN + ci];
            int lr = tid / 34, lc = tid % 34;
            int gr = row_base - 1 + lr, gc = lc - 1;
            float v = 0.f;
            if (gr >= 0 && gr < HH && gc >= 0 && gc < WW)
                v = xn[(size_t)ci * (HH * WW) + gr * WW + gc] * s;
            xin[lr][lc] = v;
        }
        for (int idx = tid; idx < 576; idx += 256) {
            int co = idx / 9, k = idx % 9;
            wsh[k][co] = weight[(size_t)(co_base + co) * (CIN * 9) + ci * 9 + k];
        }
        __syncthreads();
        float xr[6][3];
        #pragma unroll
        for (int r = 0; r < 6; r++)
            #pragma unroll
            for (int kw = 0; kw < 3; kw++) xr[r][kw] = xin[r][c + kw];
        #pragma unroll
        for (int j = 0; j < 8; j++) {
            float wv[9];
            #pragma unroll
            for (int k = 0; k < 9; k++) wv[k] = wsh[k][sub * 8 + j];
            #pragma unroll
            for (int g = 0; g < 4; g++)
                #pragma unroll
                for (int kh = 0; kh < 3; kh++)
                    #pragma unroll
                    for (int kw = 0; kw < 3; kw++)
                        acc[j][g] += xr[g + kh][kw] * wv[kh * 3 + kw];
        }
        __syncthreads();
    }
    float gm = gmul[n];
    #pragma unroll
    for (int j = 0; j < 8; j++) {
        int co = co_base + sub * 8 + j;
        float fb = bias[co] * gm;
        #pragma unroll
        for (int g = 0; g < 4; g++)
            out[(((size_t)n * COUT + co) * HH + (row_base + g)) * WW + c] = acc[j][g] + fb;
    }
}

extern "C" void kernel_launch(void* const* d_in, const int* in_sizes, int n_in,
                              void* d_out, int out_size, void* d_ws, size_t ws_size,
                              hipStream_t stream) {
    const float* x       = (const float*)d_in[0];
    const float* weight  = (const float*)d_in[1];
    const float* bias    = (const float*)d_in[2];
    const float* tconv_w = (const float*)d_in[3];
    const float* tconv_b = (const float*)d_in[4];
    const float* fc_w    = (const float*)d_in[5];
    const float* fc_b    = (const float*)d_in[6];
    float* out = (float*)d_out;

    char* wsb = (char*)d_ws;
    float* pooled = (float*)wsb;                       // 16384 f
    float* scale  = pooled + NN * CIN;                 // 16384 f
    float* gmul   = scale + NN * CIN;                  // 64 f
    const size_t XS_OFF = 131328;                      // bytes, 16-aligned
    const size_t XS_BYTES = (size_t)NN * 34 * 34 * CIN * 2;   // 37,879,808
    const size_t WB_OFF = XS_OFF + XS_BYTES;
    const size_t WB_BYTES = (size_t)9 * COUT * CIN * 2;       // 1,179,648
    u16* xs = (u16*)(wsb + XS_OFF);
    u16* wb = (u16*)(wsb + WB_OFF);

    pool_kernel<<<NN * CIN, 256, 0, stream>>>(x, pooled);
    calib_kernel<<<NN, 256, 0, stream>>>(pooled, tconv_w, tconv_b, fc_w, fc_b, scale, gmul);

    if (ws_size >= WB_OFF + WB_BYTES) {
        xs_prep_kernel<<<NN * 32, 256, 0, stream>>>(x, scale, xs);
        border_kernel<<<NN, 256, 0, stream>>>(xs);
        wprep_kernel<<<COUT, 256, 0, stream>>>(weight, wb);
        conv_mfma_kernel<<<NN * 4 * 4, 256, 0, stream>>>(xs, wb, bias, gmul, out);
    } else {
        conv_kernel<<<NN * 32, 256, 0, stream>>>(x, weight, bias, scale, gmul, out);
    }
}

// Round 3
// 141.596 us; speedup vs baseline: 8.4725x; 1.0501x over previous
//
#include <hip/hip_runtime.h>
#include <hip/hip_bf16.h>

#define CIN 256
#define COUT 256
#define HH 32
#define WW 32
#define LL 4
#define NN 64   // B*L

typedef unsigned short u16;
typedef __attribute__((ext_vector_type(8))) short short8;   // 8 bf16 (4 VGPRs)
typedef __attribute__((ext_vector_type(4))) float f32x4;

static __device__ __forceinline__ u16 f2bf(float f) {
    __hip_bfloat16 h = __float2bfloat16(f);
    return *reinterpret_cast<u16*>(&h);
}

// ---------------- Kernel 1: spatial mean pool ----------------
__global__ __launch_bounds__(256) void pool_kernel(const float* __restrict__ x,
                                                   float* __restrict__ pooled) {
    int blk = blockIdx.x;                    // n*CIN + ci
    const float* src = x + (size_t)blk * (HH * WW);
    int tid = threadIdx.x;
    float4 v = ((const float4*)src)[tid];
    float s = v.x + v.y + v.z + v.w;
    #pragma unroll
    for (int off = 32; off > 0; off >>= 1) s += __shfl_down(s, off, 64);
    __shared__ float ws[4];
    if ((tid & 63) == 0) ws[tid >> 6] = s;
    __syncthreads();
    if (tid == 0) pooled[blk] = (ws[0] + ws[1] + ws[2] + ws[3]) * (1.0f / (HH * WW));
}

// ---------------- Kernel 2: temporal calib + gate ----------------
__global__ __launch_bounds__(256) void calib_kernel(const float* __restrict__ pooled,
                                                    const float* __restrict__ tconv_w,
                                                    const float* __restrict__ tconv_b,
                                                    const float* __restrict__ fc_w,
                                                    const float* __restrict__ fc_b,
                                                    float* __restrict__ scale,
                                                    float* __restrict__ gmul) {
    int n = blockIdx.x;
    int b = n / LL, t = n % LL;
    int i0 = max(t - 2, 0), i1 = max(t - 1, 0), i2 = t;
    __shared__ float p[3][CIN];
    int tid = threadIdx.x;
    p[0][tid] = pooled[(b * LL + i0) * CIN + tid];
    p[1][tid] = pooled[(b * LL + i1) * CIN + tid];
    p[2][tid] = pooled[(b * LL + i2) * CIN + tid];
    __syncthreads();
    float acc = 0.f;
    for (int ci = 0; ci < CIN; ci++) {
        const float* w = tconv_w + ((size_t)tid * CIN + ci) * 3;
        acc += p[0][ci] * w[0] + p[1][ci] * w[1] + p[2][ci] * w[2];
    }
    scale[n * CIN + tid] = acc + tconv_b[tid] + 1.0f;
    const float* fw = fc_w + tid * 3;
    float g = p[0][tid] * fw[0] + p[1][tid] * fw[1] + p[2][tid] * fw[2];
    #pragma unroll
    for (int off = 32; off > 0; off >>= 1) g += __shfl_down(g, off, 64);
    __shared__ float gw[4];
    if ((tid & 63) == 0) gw[tid >> 6] = g;
    __syncthreads();
    if (tid == 0) gmul[n] = gw[0] + gw[1] + gw[2] + gw[3] + fc_b[0] + 1.0f;
}

// ---------------- Kernel 3a: xs2[n][ko(32)][pos(34*34)][8] = bf16(x*scale), ko = ci/8
__global__ __launch_bounds__(256) void xs_prep_kernel(const float* __restrict__ x,
                                                      const float* __restrict__ scale,
                                                      u16* __restrict__ xs) {
    int blk = blockIdx.x;            // n*32 + h
    int n = blk >> 5, h = blk & 31;
    __shared__ float tile[64][33];
    int tid = threadIdx.x;
    for (int c0 = 0; c0 < CIN; c0 += 64) {
        #pragma unroll
        for (int r = 0; r < 8; r++) {
            int idx = r * 256 + tid;             // 2048 = 64ci x 32w
            int ci = idx >> 5, w = idx & 31;
            tile[ci][w] = x[(((size_t)n * CIN + c0 + ci) * HH + h) * WW + w]
                          * scale[n * CIN + c0 + ci];
        }
        __syncthreads();
        // 256 units: o = tid>>5 (octet within chunk), w = tid&31
        {
            int o = tid >> 5, w = tid & 31;
            short8 v;
            #pragma unroll
            for (int e = 0; e < 8; e++) v[e] = (short)f2bf(tile[o * 8 + e][w]);
            int ko = (c0 >> 3) + o;
            size_t unit = ((size_t)n * 32 + ko) * (34 * 34) + (size_t)(h + 1) * 34 + (w + 1);
            *(short8*)(xs + unit * 8) = v;
        }
        __syncthreads();
    }
}

// ---------------- Kernel 3b: zero the pad border of xs2 (16B per (ko,cell))
__global__ __launch_bounds__(256) void border_kernel(u16* __restrict__ xs) {
    int n = blockIdx.x;
    for (int idx = threadIdx.x; idx < 132 * 32; idx += 256) {
        int ko = idx & 31, cell = idx >> 5;
        int hp, wp;
        if (cell < 34)       { hp = 0;              wp = cell; }
        else if (cell < 68)  { hp = 33;             wp = cell - 34; }
        else if (cell < 100) { hp = cell - 68 + 1;  wp = 0; }
        else                 { hp = cell - 100 + 1; wp = 33; }
        size_t unit = ((size_t)n * 32 + ko) * (34 * 34) + (size_t)hp * 34 + wp;
        short8 z = (short8){0,0,0,0,0,0,0,0};
        *(short8*)(xs + unit * 8) = z;
    }
}

// ---------------- Kernel 3c: wb2[tap][ko(32)][co(256)][8] = bf16(weight[co][ci][tap])
__global__ __launch_bounds__(256) void wprep_kernel(const float* __restrict__ weight,
                                                    u16* __restrict__ wb) {
    int co = blockIdx.x;
    int ci = threadIdx.x;
    #pragma unroll
    for (int k = 0; k < 9; k++) {
        u16 v = f2bf(weight[((size_t)co * CIN + ci) * 9 + k]);
        size_t unit = ((size_t)k * 32 + (ci >> 3)) * COUT + co;
        wb[unit * 8 + (ci & 7)] = v;
    }
}

// ---------------- Kernel 4: MFMA implicit-GEMM conv ----------------
// Block: (n, cog of 64 co, pt of 8 output rows). 4 waves; wave = 64co x 64pos(2 rows).
// LDS layouts (16B units): A unit = (tap*4+k8)*64+co ; B unit = k8*340+pos.
// All stage writes and frag reads are lane-consecutive 16B -> conflict-free.
__global__ __launch_bounds__(256, 2) void conv_mfma_kernel(
    const u16* __restrict__ xs, const u16* __restrict__ wb,
    const float* __restrict__ bias, const float* __restrict__ gmul,
    float* __restrict__ out) {
    int blk = blockIdx.x;
    int n = blk >> 4, cog = (blk >> 2) & 3, pt = blk & 3;
    int r0 = pt * 8;
    int tid = threadIdx.x;
    int lane = tid & 63, wave = tid >> 6;
    int l15 = lane & 15, l4 = lane >> 4;   // l4 = k-octet 0..3
    int wr = wave * 2;                      // wave's output-row offset within tile

    __shared__ u16 Alds[9 * 4 * 64 * 8];    // 2304 units = 36864 B
    __shared__ u16 Blds[4 * 340 * 8];       // 1360 units = 21760 B

    f32x4 acc[4][4];
    #pragma unroll
    for (int m = 0; m < 4; m++)
        #pragma unroll
        for (int nr = 0; nr < 4; nr++) acc[m][nr] = (f32x4){0.f, 0.f, 0.f, 0.f};

    for (int kc = 0; kc < 8; kc++) {
        __syncthreads();
        // ---- stage A: 2304 units; u -> tap=u>>8, k8=(u>>6)&3, co=u&63; LDS linear
        #pragma unroll
        for (int r = 0; r < 9; r++) {
            int u = r * 256 + tid;
            int tap = u >> 8, k8 = (u >> 6) & 3, co = u & 63;
            size_t gu = ((size_t)tap * 32 + kc * 4 + k8) * COUT + cog * 64 + co;
            short8 v = *(const short8*)(wb + gu * 8);
            *(short8*)(Alds + (size_t)u * 8) = v;
        }
        // ---- stage B: 1360 units; u -> k8=u/340, pos=u%340; LDS linear
        #pragma unroll
        for (int r = 0; r < 6; r++) {
            int u = r * 256 + tid;
            if (u < 1360) {
                int k8 = u / 340, pos = u - k8 * 340;
                size_t gu = ((size_t)n * 32 + kc * 4 + k8) * (34 * 34) + (size_t)r0 * 34 + pos;
                short8 v = *(const short8*)(xs + gu * 8);
                *(short8*)(Blds + (size_t)u * 8) = v;
            }
        }
        __syncthreads();

        #pragma unroll
        for (int tp = 0; tp < 9; tp++) {
            const int dh = tp / 3, dw = tp % 3;
            short8 af[4], bf[4];
            #pragma unroll
            for (int m = 0; m < 4; m++) {
                int u = (tp * 4 + l4) * 64 + m * 16 + l15;
                af[m] = *(const short8*)(Alds + (size_t)u * 8);
            }
            #pragma unroll
            for (int nr = 0; nr < 4; nr++) {
                int rr = nr >> 1, ch = nr & 1;
                int pos = (wr + rr + dh) * 34 + ch * 16 + l15 + dw;
                int u = l4 * 340 + pos;
                bf[nr] = *(const short8*)(Blds + (size_t)u * 8);
            }
            #pragma unroll
            for (int m = 0; m < 4; m++)
                #pragma unroll
                for (int nr = 0; nr < 4; nr++)
                    acc[m][nr] = __builtin_amdgcn_mfma_f32_16x16x32_bf16(af[m], bf[nr], acc[m][nr], 0, 0, 0);
        }
    }

    // ---- epilogue: D row=(l>>4)*4+j (co), col=l&15 (pos)
    float gm = gmul[n];
    #pragma unroll
    for (int m = 0; m < 4; m++) {
        #pragma unroll
        for (int nr = 0; nr < 4; nr++) {
            int rr = nr >> 1, ch = nr & 1;
            int orow = r0 + wr + rr;
            #pragma unroll
            for (int j = 0; j < 4; j++) {
                int co = cog * 64 + m * 16 + l4 * 4 + j;
                out[(((size_t)n * COUT + co) * HH + orow) * WW + ch * 16 + l15] =
                    acc[m][nr][j] + bias[co] * gm;
            }
        }
    }
}

// ---------------- Fallback fp32 direct conv (if ws too small) ----------------
__global__ __launch_bounds__(256) void conv_kernel(const float* __restrict__ x,
                                                   const float* __restrict__ weight,
                                                   const float* __restrict__ bias,
                                                   const float* __restrict__ scale,
                                                   const float* __restrict__ gmul,
                                                   float* __restrict__ out) {
    int blk = blockIdx.x;
    int n   = blk >> 5;
    int cog = (blk >> 3) & 3;
    int rg  = blk & 7;
    int co_base  = cog * 64;
    int row_base = rg * 4;
    int tid = threadIdx.x;
    int c   = tid & 31;
    int sub = tid >> 5;

    __shared__ float xin[6][34];
    __shared__ float wsh[9][65];

    float acc[8][4];
    #pragma unroll
    for (int j = 0; j < 8; j++)
        #pragma unroll
        for (int g = 0; g < 4; g++) acc[j][g] = 0.f;

    const float* xn = x + (size_t)n * CIN * HH * WW;

    for (int ci = 0; ci < CIN; ci++) {
        if (tid < 204) {
            float s = scale[n * CIN + ci];
            int lr = tid / 34, lc = tid % 34;
            int gr = row_base - 1 + lr, gc = lc - 1;
            float v = 0.f;
            if (gr >= 0 && gr < HH && gc >= 0 && gc < WW)
                v = xn[(size_t)ci * (HH * WW) + gr * WW + gc] * s;
            xin[lr][lc] = v;
        }
        for (int idx = tid; idx < 576; idx += 256) {
            int co = idx / 9, k = idx % 9;
            wsh[k][co] = weight[(size_t)(co_base + co) * (CIN * 9) + ci * 9 + k];
        }
        __syncthreads();
        float xr[6][3];
        #pragma unroll
        for (int r = 0; r < 6; r++)
            #pragma unroll
            for (int kw = 0; kw < 3; kw++) xr[r][kw] = xin[r][c + kw];
        #pragma unroll
        for (int j = 0; j < 8; j++) {
            float wv[9];
            #pragma unroll
            for (int k = 0; k < 9; k++) wv[k] = wsh[k][sub * 8 + j];
            #pragma unroll
            for (int g = 0; g < 4; g++)
                #pragma unroll
                for (int kh = 0; kh < 3; kh++)
                    #pragma unroll
                    for (int kw = 0; kw < 3; kw++)
                        acc[j][g] += xr[g + kh][kw] * wv[kh * 3 + kw];
        }
        __syncthreads();
    }
    float gm = gmul[n];
    #pragma unroll
    for (int j = 0; j < 8; j++) {
        int co = co_base + sub * 8 + j;
        float fb = bias[co] * gm;
        #pragma unroll
        for (int g = 0; g < 4; g++)
            out[(((size_t)n * COUT + co) * HH + (row_base + g)) * WW + c] = acc[j][g] + fb;
    }
}

extern "C" void kernel_launch(void* const* d_in, const int* in_sizes, int n_in,
                              void* d_out, int out_size, void* d_ws, size_t ws_size,
                              hipStream_t stream) {
    const float* x       = (const float*)d_in[0];
    const float* weight  = (const float*)d_in[1];
    const float* bias    = (const float*)d_in[2];
    const float* tconv_w = (const float*)d_in[3];
    const float* tconv_b = (const float*)d_in[4];
    const float* fc_w    = (const float*)d_in[5];
    const float* fc_b    = (const float*)d_in[6];
    float* out = (float*)d_out;

    char* wsb = (char*)d_ws;
    float* pooled = (float*)wsb;                       // 16384 f
    float* scale  = pooled + NN * CIN;                 // 16384 f
    float* gmul   = scale + NN * CIN;                  // 64 f
    const size_t XS_OFF = 131328;                      // bytes, 16-aligned
    const size_t XS_BYTES = (size_t)NN * 32 * 34 * 34 * 8 * 2;   // 37,879,808
    const size_t WB_OFF = XS_OFF + XS_BYTES;
    const size_t WB_BYTES = (size_t)9 * 32 * COUT * 8 * 2;       // 1,179,648
    u16* xs = (u16*)(wsb + XS_OFF);
    u16* wb = (u16*)(wsb + WB_OFF);

    pool_kernel<<<NN * CIN, 256, 0, stream>>>(x, pooled);
    calib_kernel<<<NN, 256, 0, stream>>>(pooled, tconv_w, tconv_b, fc_w, fc_b, scale, gmul);

    if (ws_size >= WB_OFF + WB_BYTES) {
        xs_prep_kernel<<<NN * 32, 256, 0, stream>>>(x, scale, xs);
        border_kernel<<<NN, 256, 0, stream>>>(xs);
        wprep_kernel<<<COUT, 256, 0, stream>>>(weight, wb);
        conv_mfma_kernel<<<NN * 4 * 4, 256, 0, stream>>>(xs, wb, bias, gmul, out);
    } else {
        conv_kernel<<<NN * 32, 256, 0, stream>>>(x, weight, bias, scale, gmul, out);
    }
}

// Round 4
// 131.974 us; speedup vs baseline: 9.0902x; 1.0729x over previous
//
#include <hip/hip_runtime.h>
#include <hip/hip_bf16.h>

#define CIN 256
#define COUT 256
#define HH 32
#define WW 32
#define LL 4
#define NN 64   // B*L

typedef unsigned short u16;
typedef __attribute__((ext_vector_type(8))) short short8;   // 8 bf16 (4 VGPRs)
typedef __attribute__((ext_vector_type(4))) float f32x4;

typedef const __attribute__((address_space(1))) void gvoid_t;
typedef __attribute__((address_space(3))) void svoid_t;

static __device__ __forceinline__ u16 f2bf(float f) {
    __hip_bfloat16 h = __float2bfloat16(f);
    return *reinterpret_cast<u16*>(&h);
}

// ---------------- Kernel 1: spatial mean pool ----------------
__global__ __launch_bounds__(256) void pool_kernel(const float* __restrict__ x,
                                                   float* __restrict__ pooled) {
    int blk = blockIdx.x;                    // n*CIN + ci
    const float* src = x + (size_t)blk * (HH * WW);
    int tid = threadIdx.x;
    float4 v = ((const float4*)src)[tid];
    float s = v.x + v.y + v.z + v.w;
    #pragma unroll
    for (int off = 32; off > 0; off >>= 1) s += __shfl_down(s, off, 64);
    __shared__ float ws[4];
    if ((tid & 63) == 0) ws[tid >> 6] = s;
    __syncthreads();
    if (tid == 0) pooled[blk] = (ws[0] + ws[1] + ws[2] + ws[3]) * (1.0f / (HH * WW));
}

// ---------------- Kernel 2: temporal calib + gate ----------------
__global__ __launch_bounds__(256) void calib_kernel(const float* __restrict__ pooled,
                                                    const float* __restrict__ tconv_w,
                                                    const float* __restrict__ tconv_b,
                                                    const float* __restrict__ fc_w,
                                                    const float* __restrict__ fc_b,
                                                    float* __restrict__ scale,
                                                    float* __restrict__ gmul) {
    int n = blockIdx.x;
    int b = n / LL, t = n % LL;
    int i0 = max(t - 2, 0), i1 = max(t - 1, 0), i2 = t;
    __shared__ float p[3][CIN];
    int tid = threadIdx.x;
    p[0][tid] = pooled[(b * LL + i0) * CIN + tid];
    p[1][tid] = pooled[(b * LL + i1) * CIN + tid];
    p[2][tid] = pooled[(b * LL + i2) * CIN + tid];
    __syncthreads();
    float acc = 0.f;
    for (int ci = 0; ci < CIN; ci++) {
        const float* w = tconv_w + ((size_t)tid * CIN + ci) * 3;
        acc += p[0][ci] * w[0] + p[1][ci] * w[1] + p[2][ci] * w[2];
    }
    scale[n * CIN + tid] = acc + tconv_b[tid] + 1.0f;
    const float* fw = fc_w + tid * 3;
    float g = p[0][tid] * fw[0] + p[1][tid] * fw[1] + p[2][tid] * fw[2];
    #pragma unroll
    for (int off = 32; off > 0; off >>= 1) g += __shfl_down(g, off, 64);
    __shared__ float gw[4];
    if ((tid & 63) == 0) gw[tid >> 6] = g;
    __syncthreads();
    if (tid == 0) gmul[n] = gw[0] + gw[1] + gw[2] + gw[3] + fc_b[0] + 1.0f;
}

// ---------------- Kernel 3a: xs2[n][ko(32)][pos(34*34)][8] = bf16(x*scale), ko = ci/8
__global__ __launch_bounds__(256) void xs_prep_kernel(const float* __restrict__ x,
                                                      const float* __restrict__ scale,
                                                      u16* __restrict__ xs) {
    int blk = blockIdx.x;            // n*32 + h
    int n = blk >> 5, h = blk & 31;
    __shared__ float tile[64][33];
    int tid = threadIdx.x;
    for (int c0 = 0; c0 < CIN; c0 += 64) {
        #pragma unroll
        for (int r = 0; r < 8; r++) {
            int idx = r * 256 + tid;             // 2048 = 64ci x 32w
            int ci = idx >> 5, w = idx & 31;
            tile[ci][w] = x[(((size_t)n * CIN + c0 + ci) * HH + h) * WW + w]
                          * scale[n * CIN + c0 + ci];
        }
        __syncthreads();
        {
            int o = tid >> 5, w = tid & 31;
            short8 v;
            #pragma unroll
            for (int e = 0; e < 8; e++) v[e] = (short)f2bf(tile[o * 8 + e][w]);
            int ko = (c0 >> 3) + o;
            size_t unit = ((size_t)n * 32 + ko) * (34 * 34) + (size_t)(h + 1) * 34 + (w + 1);
            *(short8*)(xs + unit * 8) = v;
        }
        __syncthreads();
    }
}

// ---------------- Kernel 3b: zero the pad border of xs2
__global__ __launch_bounds__(256) void border_kernel(u16* __restrict__ xs) {
    int n = blockIdx.x;
    for (int idx = threadIdx.x; idx < 132 * 32; idx += 256) {
        int ko = idx & 31, cell = idx >> 5;
        int hp, wp;
        if (cell < 34)       { hp = 0;              wp = cell; }
        else if (cell < 68)  { hp = 33;             wp = cell - 34; }
        else if (cell < 100) { hp = cell - 68 + 1;  wp = 0; }
        else                 { hp = cell - 100 + 1; wp = 33; }
        size_t unit = ((size_t)n * 32 + ko) * (34 * 34) + (size_t)hp * 34 + wp;
        short8 z = (short8){0,0,0,0,0,0,0,0};
        *(short8*)(xs + unit * 8) = z;
    }
}

// ---------------- Kernel 3c: wb2[tap][ko(32)][co(256)][8]
__global__ __launch_bounds__(256) void wprep_kernel(const float* __restrict__ weight,
                                                    u16* __restrict__ wb) {
    int co = blockIdx.x;
    int ci = threadIdx.x;
    #pragma unroll
    for (int k = 0; k < 9; k++) {
        u16 v = f2bf(weight[((size_t)co * CIN + ci) * 9 + k]);
        size_t unit = ((size_t)k * 32 + (ci >> 3)) * COUT + co;
        wb[unit * 8 + (ci & 7)] = v;
    }
}

// ---------------- Kernel 4: MFMA implicit-GEMM conv ----------------
// Block = (n, cog of 64 co, pg of 16 output rows). 4 waves stacked in pos;
// wave = 64co x 128pos (4 output rows x 32 cols). acc[4 m][4 r][2 ch].
// A-LDS unit = (tap*4+k8)*66 + co   (stride 66 -> l4 groups spread mod 128)
// B-LDS unit = u (linear staging);  logical u = k8*612 + lrow*34 + lcol, lrow 0..17
// Staging via global_load_lds width-16: dest linear in lane, src per-lane.
__global__ __launch_bounds__(256, 2) void conv_mfma_kernel(
    const u16* __restrict__ xs, const u16* __restrict__ wb,
    const float* __restrict__ bias, const float* __restrict__ gmul,
    float* __restrict__ out) {
    int blk = blockIdx.x;
    int n = blk >> 3, cog = (blk >> 1) & 3, pg = blk & 1;
    int r0 = pg * 16;
    int tid = threadIdx.x;
    int lane = tid & 63, wave = tid >> 6;
    int l15 = lane & 15, l4 = lane >> 4;
    int w4 = wave * 4;                  // wave's output-row offset in block tile

    __shared__ u16 Alds[9 * 4 * 66 * 8];    // 2376 units = 38016 B
    __shared__ u16 Blds[2560 * 8];          // 2448 used + pad = 40960 B

    f32x4 acc[4][4][2];
    #pragma unroll
    for (int m = 0; m < 4; m++)
        #pragma unroll
        for (int r = 0; r < 4; r++)
            #pragma unroll
            for (int ch = 0; ch < 2; ch++) acc[m][r][ch] = (f32x4){0.f, 0.f, 0.f, 0.f};

    for (int kc = 0; kc < 8; kc++) {
        __syncthreads();
        // ---- stage A: 9 iters; tap=r, k8=wave, co=lane (all wave-uniform but co)
        #pragma unroll
        for (int r = 0; r < 9; r++) {
            size_t gu = ((size_t)(r * 32 + kc * 4 + wave)) * COUT + cog * 64 + lane;
            __builtin_amdgcn_global_load_lds((gvoid_t*)(wb + gu * 8),
                                             (svoid_t*)(Alds + (size_t)(r * 4 + wave) * 66 * 8),
                                             16, 0, 0);
        }
        // ---- stage B: 10 iters; u linear; clamp tail into pad region
        #pragma unroll
        for (int r = 0; r < 10; r++) {
            int u = r * 256 + tid;
            int ue = u < 2448 ? u : 2447;
            int k8 = ue / 612;
            int rem = ue - k8 * 612;
            int lrow = rem / 34;
            int lcol = rem - lrow * 34;
            size_t gu = ((size_t)n * 32 + kc * 4 + k8) * (34 * 34) + (size_t)(r0 + lrow) * 34 + lcol;
            __builtin_amdgcn_global_load_lds((gvoid_t*)(xs + gu * 8),
                                             (svoid_t*)(Blds + (size_t)(r * 256 + wave * 64) * 8),
                                             16, 0, 0);
        }
        __syncthreads();

        #pragma unroll
        for (int dw = 0; dw < 3; dw++) {
            // hoist B frags: 6 rows x 2 ch, reused across dh (row overlap)
            short8 bfr[6][2];
            #pragma unroll
            for (int j = 0; j < 6; j++)
                #pragma unroll
                for (int ch = 0; ch < 2; ch++) {
                    int u = l4 * 612 + (w4 + j) * 34 + ch * 16 + l15 + dw;
                    bfr[j][ch] = *(const short8*)(Blds + (size_t)u * 8);
                }
            #pragma unroll
            for (int dh = 0; dh < 3; dh++) {
                int tap = dh * 3 + dw;
                #pragma unroll
                for (int m = 0; m < 4; m++) {
                    int ua = (tap * 4 + l4) * 66 + m * 16 + l15;
                    short8 af = *(const short8*)(Alds + (size_t)ua * 8);
                    #pragma unroll
                    for (int r = 0; r < 4; r++)
                        #pragma unroll
                        for (int ch = 0; ch < 2; ch++)
                            acc[m][r][ch] = __builtin_amdgcn_mfma_f32_16x16x32_bf16(
                                af, bfr[r + dh][ch], acc[m][r][ch], 0, 0, 0);
                }
            }
        }
    }

    // ---- epilogue: D row=(l>>4)*4+j -> co, col=l&15 -> pos
    float gm = gmul[n];
    #pragma unroll
    for (int m = 0; m < 4; m++) {
        #pragma unroll
        for (int r = 0; r < 4; r++) {
            int orow = r0 + w4 + r;
            #pragma unroll
            for (int ch = 0; ch < 2; ch++) {
                #pragma unroll
                for (int j = 0; j < 4; j++) {
                    int co = cog * 64 + m * 16 + l4 * 4 + j;
                    out[(((size_t)n * COUT + co) * HH + orow) * WW + ch * 16 + l15] =
                        acc[m][r][ch][j] + bias[co] * gm;
                }
            }
        }
    }
}

// ---------------- Fallback fp32 direct conv (if ws too small) ----------------
__global__ __launch_bounds__(256) void conv_kernel(const float* __restrict__ x,
                                                   const float* __restrict__ weight,
                                                   const float* __restrict__ bias,
                                                   const float* __restrict__ scale,
                                                   const float* __restrict__ gmul,
                                                   float* __restrict__ out) {
    int blk = blockIdx.x;
    int n   = blk >> 5;
    int cog = (blk >> 3) & 3;
    int rg  = blk & 7;
    int co_base  = cog * 64;
    int row_base = rg * 4;
    int tid = threadIdx.x;
    int c   = tid & 31;
    int sub = tid >> 5;

    __shared__ float xin[6][34];
    __shared__ float wsh[9][65];

    float acc[8][4];
    #pragma unroll
    for (int j = 0; j < 8; j++)
        #pragma unroll
        for (int g = 0; g < 4; g++) acc[j][g] = 0.f;

    const float* xn = x + (size_t)n * CIN * HH * WW;

    for (int ci = 0; ci < CIN; ci++) {
        if (tid < 204) {
            float s = scale[n * CIN + ci];
            int lr = tid / 34, lc = tid % 34;
            int gr = row_base - 1 + lr, gc = lc - 1;
            float v = 0.f;
            if (gr >= 0 && gr < HH && gc >= 0 && gc < WW)
                v = xn[(size_t)ci * (HH * WW) + gr * WW + gc] * s;
            xin[lr][lc] = v;
        }
        for (int idx = tid; idx < 576; idx += 256) {
            int co = idx / 9, k = idx % 9;
            wsh[k][co] = weight[(size_t)(co_base + co) * (CIN * 9) + ci * 9 + k];
        }
        __syncthreads();
        float xr[6][3];
        #pragma unroll
        for (int r = 0; r < 6; r++)
            #pragma unroll
            for (int kw = 0; kw < 3; kw++) xr[r][kw] = xin[r][c + kw];
        #pragma unroll
        for (int j = 0; j < 8; j++) {
            float wv[9];
            #pragma unroll
            for (int k = 0; k < 9; k++) wv[k] = wsh[k][sub * 8 + j];
            #pragma unroll
            for (int g = 0; g < 4; g++)
                #pragma unroll
                for (int kh = 0; kh < 3; kh++)
                    #pragma unroll
                    for (int kw = 0; kw < 3; kw++)
                        acc[j][g] += xr[g + kh][kw] * wv[kh * 3 + kw];
        }
        __syncthreads();
    }
    float gm = gmul[n];
    #pragma unroll
    for (int j = 0; j < 8; j++) {
        int co = co_base + sub * 8 + j;
        float fb = bias[co] * gm;
        #pragma unroll
        for (int g = 0; g < 4; g++)
            out[(((size_t)n * COUT + co) * HH + (row_base + g)) * WW + c] = acc[j][g] + fb;
    }
}

extern "C" void kernel_launch(void* const* d_in, const int* in_sizes, int n_in,
                              void* d_out, int out_size, void* d_ws, size_t ws_size,
                              hipStream_t stream) {
    const float* x       = (const float*)d_in[0];
    const float* weight  = (const float*)d_in[1];
    const float* bias    = (const float*)d_in[2];
    const float* tconv_w = (const float*)d_in[3];
    const float* tconv_b = (const float*)d_in[4];
    const float* fc_w    = (const float*)d_in[5];
    const float* fc_b    = (const float*)d_in[6];
    float* out = (float*)d_out;

    char* wsb = (char*)d_ws;
    float* pooled = (float*)wsb;                       // 16384 f
    float* scale  = pooled + NN * CIN;                 // 16384 f
    float* gmul   = scale + NN * CIN;                  // 64 f
    const size_t XS_OFF = 131328;                      // bytes, 16-aligned
    const size_t XS_BYTES = (size_t)NN * 32 * 34 * 34 * 8 * 2;   // 37,879,808
    const size_t WB_OFF = XS_OFF + XS_BYTES;
    const size_t WB_BYTES = (size_t)9 * 32 * COUT * 8 * 2;       // 1,179,648
    u16* xs = (u16*)(wsb + XS_OFF);
    u16* wb = (u16*)(wsb + WB_OFF);

    pool_kernel<<<NN * CIN, 256, 0, stream>>>(x, pooled);
    calib_kernel<<<NN, 256, 0, stream>>>(pooled, tconv_w, tconv_b, fc_w, fc_b, scale, gmul);

    if (ws_size >= WB_OFF + WB_BYTES) {
        xs_prep_kernel<<<NN * 32, 256, 0, stream>>>(x, scale, xs);
        border_kernel<<<NN, 256, 0, stream>>>(xs);
        wprep_kernel<<<COUT, 256, 0, stream>>>(weight, wb);
        conv_mfma_kernel<<<NN * 4 * 2, 256, 0, stream>>>(xs, wb, bias, gmul, out);
    } else {
        conv_kernel<<<NN * 32, 256, 0, stream>>>(x, weight, bias, scale, gmul, out);
    }
}